// Round 1
// baseline (315.224 us; speedup 1.0000x reference)
//
#include <hip/hip_runtime.h>

// ---------------------------------------------------------------------------
// TemporalHyperedge: loss[b] = 0.2 * sum_n ||cur[b]@r_proj - W@pre[b]||_2
//                              + sum_n (max_m W[n,m] + 0.001*||W[n,:]||_2)
// W = incidence_m masked to > 0.01. Output = [loss(32) , incidence_m(2048^2)].
//
// Strategy: single K=2304 bf16 MFMA GEMM per (b, n-tile, d-tile):
//   diff[b,n,d] = sum_k Aext[n,k] * Bext[b,k,d]
//   Aext = [ -W (2048 cols) | cur[b] (256 cols) ]   (row-major, K contiguous)
//   Bext^T staged as [ preT[b] (d,m) ; rprojT (d,e) ] (K contiguous per d-row)
// Epilogue reduces sum_d diff^2 into S[b,n]; finalize does sqrt+sum.
// ---------------------------------------------------------------------------

typedef __attribute__((ext_vector_type(8))) short bf16x8;
typedef __attribute__((ext_vector_type(4))) float f32x4;

__device__ __forceinline__ unsigned short f2bf(float f) {
    union { float f; unsigned u; } x; x.f = f;
    unsigned r = x.u + 0x7fffu + ((x.u >> 16) & 1u);   // RNE
    return (unsigned short)(r >> 16);
}

#define GLL16(g, l)                                                         \
    __builtin_amdgcn_global_load_lds(                                       \
        (const __attribute__((address_space(1))) void*)(g),                 \
        (__attribute__((address_space(3))) void*)(l), 16, 0, 0)

// --------------------------------------------------------------------------
// prep_w: per incidence row: copy to output, write -masked bf16, accumulate
// Csum += max|W_row| + 0.001*||W_row||_2
// --------------------------------------------------------------------------
__global__ void prep_w(const float* __restrict__ inc, float* __restrict__ out_inc,
                       unsigned short* __restrict__ Wneg, float* __restrict__ csum) {
    const int row = blockIdx.x;
    const float4* src = (const float4*)(inc + (size_t)row * 2048);
    float4* dst = (float4*)(out_inc + (size_t)row * 2048);
    ushort4* wp = (ushort4*)(Wneg + (size_t)row * 2048);
    float lmax = 0.f, ss = 0.f;
#pragma unroll
    for (int it = 0; it < 2; ++it) {
        int i = it * 256 + threadIdx.x;          // 512 float4 per row
        float4 v = src[i];
        dst[i] = v;
        float w0 = v.x > 0.01f ? v.x : 0.f;
        float w1 = v.y > 0.01f ? v.y : 0.f;
        float w2 = v.z > 0.01f ? v.z : 0.f;
        float w3 = v.w > 0.01f ? v.w : 0.f;
        ushort4 p;
        p.x = f2bf(-w0); p.y = f2bf(-w1); p.z = f2bf(-w2); p.w = f2bf(-w3);
        wp[i] = p;
        lmax = fmaxf(lmax, fmaxf(fmaxf(w0, w1), fmaxf(w2, w3)));
        ss += w0 * w0 + w1 * w1 + w2 * w2 + w3 * w3;
    }
#pragma unroll
    for (int off = 32; off; off >>= 1) {
        lmax = fmaxf(lmax, __shfl_down(lmax, off));
        ss += __shfl_down(ss, off);
    }
    __shared__ float smax[4], ssum[4];
    int wv = threadIdx.x >> 6, ln = threadIdx.x & 63;
    if (ln == 0) { smax[wv] = lmax; ssum[wv] = ss; }
    __syncthreads();
    if (threadIdx.x == 0) {
        float m = fmaxf(fmaxf(smax[0], smax[1]), fmaxf(smax[2], smax[3]));
        float s = ssum[0] + ssum[1] + ssum[2] + ssum[3];
        atomicAdd(csum, m + 0.001f * sqrtf(s));
    }
}

// --------------------------------------------------------------------------
// conv_cur: flat f32 -> bf16 (vectorized x4)
// --------------------------------------------------------------------------
__global__ void conv_cur(const float* __restrict__ src, unsigned short* __restrict__ dst,
                         int n4) {
    int i = blockIdx.x * blockDim.x + threadIdx.x;
    if (i < n4) {
        float4 v = ((const float4*)src)[i];
        ushort4 p;
        p.x = f2bf(v.x); p.y = f2bf(v.y); p.z = f2bf(v.z); p.w = f2bf(v.w);
        ((ushort4*)dst)[i] = p;
    }
}

// --------------------------------------------------------------------------
// transpose_conv: src f32 (R,C) row-major -> dst bf16 (C,R) row-major, batched
// 64x64 tiles via LDS (pad 68 keeps ushort4 reads 8B-aligned).
// --------------------------------------------------------------------------
__global__ void transpose_conv(const float* __restrict__ src,
                               unsigned short* __restrict__ dst, int R, int C) {
    const int b = blockIdx.z;
    const int r0 = blockIdx.x * 64, c0 = blockIdx.y * 64;
    src += (size_t)b * R * C;
    dst += (size_t)b * R * C;
    __shared__ unsigned short tile[64][68];
    const int t = threadIdx.x;
    const int fc = (t & 15) * 4;
#pragma unroll
    for (int it = 0; it < 4; ++it) {
        int fr = (t >> 4) + it * 16;
        float4 v = *(const float4*)(src + (size_t)(r0 + fr) * C + c0 + fc);
        tile[fc + 0][fr] = f2bf(v.x);
        tile[fc + 1][fr] = f2bf(v.y);
        tile[fc + 2][fr] = f2bf(v.z);
        tile[fc + 3][fr] = f2bf(v.w);
    }
    __syncthreads();
    const int sc = (t & 15) * 4;
#pragma unroll
    for (int it = 0; it < 4; ++it) {
        int cr = (t >> 4) + it * 16;
        ushort4 p;
        p.x = tile[cr][sc + 0]; p.y = tile[cr][sc + 1];
        p.z = tile[cr][sc + 2]; p.w = tile[cr][sc + 3];
        *(ushort4*)(dst + (size_t)(c0 + cr) * R + r0 + sc) = p;
    }
}

// --------------------------------------------------------------------------
// gemm_diff: 128x128 tile, BK=32, K=2304 (= 2048 W|pre part + 256 cur|rproj).
// 256 threads = 4 waves, 2x2 wave grid, 4x4 16x16x32 MFMAs per wave.
// Epilogue: per-row sum of diff^2 over this block's 128 d-cols -> atomicAdd S.
// --------------------------------------------------------------------------
__global__ __launch_bounds__(256) void gemm_diff(
    const unsigned short* __restrict__ Wneg,    // (2048,2048)
    const unsigned short* __restrict__ curb,    // (32,2048,256)
    const unsigned short* __restrict__ preT,    // (32,256,2048)
    const unsigned short* __restrict__ rprojT,  // (256,256)
    float* __restrict__ S)                      // (32,2048)
{
    const int b  = blockIdx.z;
    const int n0 = blockIdx.x * 128;
    const int d0 = blockIdx.y * 128;

    __shared__ unsigned short Al[128 * 32];
    __shared__ unsigned short Bl[128 * 32];
    __shared__ float ssq[128];

    const int tid  = threadIdx.x;
    const int w    = tid >> 6;
    const int lane = tid & 63;
    const int l16  = lane & 15;
    const int quad = lane >> 4;
    const int wm   = w >> 1, wn = w & 1;

    if (tid < 128) ssq[tid] = 0.f;

    f32x4 acc[4][4] = {};

    const unsigned short* curB = curb + (size_t)b * 2048 * 256;
    const unsigned short* preB = preT + (size_t)b * 256 * 2048;

    const int srow  = lane >> 2;        // 0..15
    const int sbyte = (lane & 3) * 16;  // bytes within 64B row-chunk

    for (int kt = 0; kt < 72; ++kt) {
        const unsigned short *ab, *bb;
        size_t as, bs;
        if (kt < 64) {
            const int k0 = kt * 32;
            ab = Wneg + (size_t)n0 * 2048 + k0; as = 2048;
            bb = preB + (size_t)d0 * 2048 + k0; bs = 2048;
        } else {
            const int kk = kt * 32 - 2048;
            ab = curB + (size_t)n0 * 256 + kk;   as = 256;
            bb = rprojT + (size_t)d0 * 256 + kk; bs = 256;
        }
        __syncthreads();  // previous tile fully consumed
#pragma unroll
        for (int j = 0; j < 2; ++j) {
            const int row = w * 32 + j * 16 + srow;
            GLL16((const char*)(ab + row * as) + sbyte, (char*)Al + w * 2048 + j * 1024);
            GLL16((const char*)(bb + row * bs) + sbyte, (char*)Bl + w * 2048 + j * 1024);
        }
        __syncthreads();  // staging visible (compiler drains vmcnt before barrier)

        bf16x8 af[4], bfr[4];
#pragma unroll
        for (int mi = 0; mi < 4; ++mi)
            af[mi] = *(const bf16x8*)(Al + (wm * 64 + mi * 16 + l16) * 32 + quad * 8);
#pragma unroll
        for (int ni = 0; ni < 4; ++ni)
            bfr[ni] = *(const bf16x8*)(Bl + (wn * 64 + ni * 16 + l16) * 32 + quad * 8);
#pragma unroll
        for (int mi = 0; mi < 4; ++mi)
#pragma unroll
            for (int ni = 0; ni < 4; ++ni)
                acc[mi][ni] = __builtin_amdgcn_mfma_f32_16x16x32_bf16(
                    af[mi], bfr[ni], acc[mi][ni], 0, 0, 0);
    }
    __syncthreads();

    // C/D layout: col = lane&15 (d), row = quad*4 + reg (n) [verified m89/m91]
#pragma unroll
    for (int mi = 0; mi < 4; ++mi)
#pragma unroll
        for (int r = 0; r < 4; ++r) {
            float s = 0.f;
#pragma unroll
            for (int ni = 0; ni < 4; ++ni) {
                float v = acc[mi][ni][r];
                s += v * v;
            }
            // reduce across the 16 d-lanes of this quad-group
            s += __shfl_xor(s, 1);
            s += __shfl_xor(s, 2);
            s += __shfl_xor(s, 4);
            s += __shfl_xor(s, 8);
            if (l16 == 0)
                atomicAdd(&ssq[wm * 64 + mi * 16 + quad * 4 + r], s);
        }
    __syncthreads();
    if (tid < 128)
        atomicAdd(&S[(size_t)b * 2048 + n0 + tid], ssq[tid]);
}

// --------------------------------------------------------------------------
// finalize: loss[b] = 0.2 * sum_n sqrt(S[b,n]) + Csum
// --------------------------------------------------------------------------
__global__ void finalize(const float* __restrict__ S, const float* __restrict__ csum,
                         float* __restrict__ out) {
    const int b = blockIdx.x;
    float s = 0.f;
    for (int i = threadIdx.x; i < 2048; i += 256)
        s += sqrtf(S[(size_t)b * 2048 + i]);
#pragma unroll
    for (int off = 32; off; off >>= 1) s += __shfl_down(s, off);
    __shared__ float sm[4];
    int wv = threadIdx.x >> 6, ln = threadIdx.x & 63;
    if (ln == 0) sm[wv] = s;
    __syncthreads();
    if (threadIdx.x == 0)
        out[b] = 0.2f * (sm[0] + sm[1] + sm[2] + sm[3]) + csum[0];
}

// --------------------------------------------------------------------------
extern "C" void kernel_launch(void* const* d_in, const int* in_sizes, int n_in,
                              void* d_out, int out_size, void* d_ws, size_t ws_size,
                              hipStream_t stream) {
    const float* cur    = (const float*)d_in[0];  // (32,2048,256)
    const float* pre    = (const float*)d_in[1];  // (32,2048,256)
    const float* r_proj = (const float*)d_in[2];  // (256,256)
    const float* inc    = (const float*)d_in[3];  // (2048,2048)
    float* out = (float*)d_out;                   // [0..31]=loss, [32..]=incidence

    char* ws = (char*)d_ws;
    // workspace layout (bytes):
    unsigned short* Wneg   = (unsigned short*)(ws + 0);          //  8 MB
    unsigned short* curb   = (unsigned short*)(ws + 8388608);    // 32 MB
    unsigned short* preT   = (unsigned short*)(ws + 41943040);   // 32 MB
    unsigned short* rprojT = (unsigned short*)(ws + 75497472);   // 128 KB
    float*          Sbuf   = (float*)(ws + 75628544);            // 256 KB
    // csum at 75890688 (4 B); total ~75.9 MB

    float* csum = (float*)(ws + 75890688);
    hipMemsetAsync(ws + 75628544, 0, 262148, stream);  // S + csum

    prep_w<<<2048, 256, 0, stream>>>(inc, out + 32, Wneg, csum);
    conv_cur<<<16384, 256, 0, stream>>>(cur, curb, 4194304);
    transpose_conv<<<dim3(32, 4, 32), 256, 0, stream>>>(pre, preT, 2048, 256);
    transpose_conv<<<dim3(4, 4, 1), 256, 0, stream>>>(r_proj, rprojT, 256, 256);
    gemm_diff<<<dim3(16, 2, 32), 256, 0, stream>>>(Wneg, curb, preT, rprojT, Sbuf);
    finalize<<<32, 256, 0, stream>>>(Sbuf, csum, out);
}

// Round 2
// 305.342 us; speedup vs baseline: 1.0324x; 1.0324x over previous
//
#include <hip/hip_runtime.h>

// ---------------------------------------------------------------------------
// TemporalHyperedge: loss[b] = 0.2 * sum_n ||cur[b]@r_proj - W@pre[b]||_2
//                              + sum_n (max_m W[n,m] + 0.001*||W[n,:]||_2)
// W = incidence_m masked to > 0.01. Output = [loss(32) , incidence_m(2048^2)].
//
// R1 change: all prep fused into ONE kernel (sections by blockIdx) — the four
// independent prep kernels were serialized on the stream and dominated the
// non-GEMM 196us. GEMM untouched (isolate the change).
// ---------------------------------------------------------------------------

typedef __attribute__((ext_vector_type(8))) short bf16x8;
typedef __attribute__((ext_vector_type(8))) unsigned short ushort8;
typedef __attribute__((ext_vector_type(4))) float f32x4;

__device__ __forceinline__ unsigned short f2bf(float f) {
    union { float f; unsigned u; } x; x.f = f;
    unsigned r = x.u + 0x7fffu + ((x.u >> 16) & 1u);   // RNE
    return (unsigned short)(r >> 16);
}

#define GLL16(g, l)                                                         \
    __builtin_amdgcn_global_load_lds(                                       \
        (const __attribute__((address_space(1))) void*)(g),                 \
        (__attribute__((address_space(3))) void*)(l), 16, 0, 0)

// --------------------------------------------------------------------------
// 64x64 f32->bf16 transpose tile helper. tile = 64 rows x 66-short pitch
// (132B rows: write banks ~2-way (free), column reads bank-stride 33 == 1 mod
// 32 -> conflict pattern ~4-way on the 8 scalar reads, acceptable).
// Output stores are 16B ushort8, fully coalesced (8 lanes x 16B = 128B rows).
// --------------------------------------------------------------------------
__device__ __forceinline__ void transpose_64x64(
    const float* __restrict__ src, unsigned short* __restrict__ dst,
    int R, int C, int r0, int c0, unsigned short* __restrict__ tile) {
    const int t = threadIdx.x;
    const int fr = t >> 4, fc = (t & 15) * 4;
#pragma unroll
    for (int it = 0; it < 4; ++it) {
        int m = fr + it * 16;
        float4 v = *(const float4*)(src + (size_t)(r0 + m) * C + c0 + fc);
        unsigned short* p = tile + m * 66 + fc;
        ushort2 a, b;
        a.x = f2bf(v.x); a.y = f2bf(v.y);
        b.x = f2bf(v.z); b.y = f2bf(v.w);
        *(ushort2*)(p) = a;
        *(ushort2*)(p + 2) = b;
    }
    __syncthreads();
#pragma unroll
    for (int pss = 0; pss < 2; ++pss) {
        int d = (t >> 3) + pss * 32;
        int m8 = (t & 7) * 8;
        unsigned short r[8];
#pragma unroll
        for (int j = 0; j < 8; ++j) r[j] = tile[(m8 + j) * 66 + d];
        ushort8 pk;
        pk[0] = r[0]; pk[1] = r[1]; pk[2] = r[2]; pk[3] = r[3];
        pk[4] = r[4]; pk[5] = r[5]; pk[6] = r[6]; pk[7] = r[7];
        *(ushort8*)(dst + (size_t)(c0 + d) * R + r0 + m8) = pk;
    }
}

// --------------------------------------------------------------------------
// prep_all — block sections:
//   [0,2048)    : incidence row: copy-out, -masked bf16 W, csum += l1+1e-3*l2
//   [2048,4096) : cur f32 -> bf16 flat convert (8 float4/thread)
//   [4096,8192) : pre (32,2048,256) -> preT (32,256,2048) bf16 transpose
//   [8192,8208) : r_proj (256,256) -> rprojT bf16 transpose
// --------------------------------------------------------------------------
__global__ __launch_bounds__(256) void prep_all(
    const float* __restrict__ inc, float* __restrict__ out_inc,
    unsigned short* __restrict__ Wneg, float* __restrict__ csum,
    const float* __restrict__ cur, unsigned short* __restrict__ curb,
    const float* __restrict__ pre, unsigned short* __restrict__ preT,
    const float* __restrict__ r_proj, unsigned short* __restrict__ rprojT) {
    __shared__ unsigned short tile[64 * 66];
    __shared__ float smax[4], ssum[4];
    const int bid = blockIdx.x;
    const int t = threadIdx.x;

    if (bid < 2048) {
        // ---- masked W + reductions + incidence copy-out ----
        const int row = bid;
        const float4* src = (const float4*)(inc + (size_t)row * 2048);
        float4* dst = (float4*)(out_inc + (size_t)row * 2048);
        ushort4* wp = (ushort4*)(Wneg + (size_t)row * 2048);
        float lmax = 0.f, ss = 0.f;
#pragma unroll
        for (int it = 0; it < 2; ++it) {
            int i = it * 256 + t;
            float4 v = src[i];
            dst[i] = v;
            float w0 = v.x > 0.01f ? v.x : 0.f;
            float w1 = v.y > 0.01f ? v.y : 0.f;
            float w2 = v.z > 0.01f ? v.z : 0.f;
            float w3 = v.w > 0.01f ? v.w : 0.f;
            ushort4 p;
            p.x = f2bf(-w0); p.y = f2bf(-w1); p.z = f2bf(-w2); p.w = f2bf(-w3);
            wp[i] = p;
            lmax = fmaxf(lmax, fmaxf(fmaxf(w0, w1), fmaxf(w2, w3)));
            ss += w0 * w0 + w1 * w1 + w2 * w2 + w3 * w3;
        }
#pragma unroll
        for (int off = 32; off; off >>= 1) {
            lmax = fmaxf(lmax, __shfl_down(lmax, off));
            ss += __shfl_down(ss, off);
        }
        int wv = t >> 6, ln = t & 63;
        if (ln == 0) { smax[wv] = lmax; ssum[wv] = ss; }
        __syncthreads();
        if (t == 0) {
            float m = fmaxf(fmaxf(smax[0], smax[1]), fmaxf(smax[2], smax[3]));
            float s = ssum[0] + ssum[1] + ssum[2] + ssum[3];
            atomicAdd(csum, m + 0.001f * sqrtf(s));
        }
    } else if (bid < 4096) {
        // ---- cur -> bf16 ----
        const size_t base = (size_t)(bid - 2048) * 2048;
#pragma unroll
        for (int it = 0; it < 8; ++it) {
            size_t i = base + it * 256 + t;
            float4 v = ((const float4*)cur)[i];
            ushort4 p;
            p.x = f2bf(v.x); p.y = f2bf(v.y); p.z = f2bf(v.z); p.w = f2bf(v.w);
            ((ushort4*)curb)[i] = p;
        }
    } else if (bid < 8192) {
        // ---- pre transpose: (2048 m,256 d) -> (256 d,2048 m), per batch ----
        const int tt = bid - 4096;
        const int b = tt >> 7;             // 32 batches
        const int mt = (tt & 127) >> 2;    // 32 m-tiles
        const int dt = tt & 3;             // 4 d-tiles
        transpose_64x64(pre + (size_t)b * 524288, preT + (size_t)b * 524288,
                        2048, 256, mt * 64, dt * 64, tile);
    } else {
        // ---- r_proj transpose (256,256) ----
        const int tt = bid - 8192;
        transpose_64x64(r_proj, rprojT, 256, 256, (tt >> 2) * 64, (tt & 3) * 64,
                        tile);
    }
}

// --------------------------------------------------------------------------
// gemm_diff: 128x128 tile, BK=32, K=2304 (2048 W|preT part + 256 cur|rprojT).
// 256 threads = 4 waves, 2x2 wave grid, 4x4 16x16x32 MFMAs per wave.
// Epilogue: per-row sum of diff^2 over this block's 128 d-cols -> atomicAdd S.
// (unchanged from R1 — 118.7us, MfmaUtil 27%)
// --------------------------------------------------------------------------
__global__ __launch_bounds__(256) void gemm_diff(
    const unsigned short* __restrict__ Wneg,    // (2048,2048)
    const unsigned short* __restrict__ curb,    // (32,2048,256)
    const unsigned short* __restrict__ preT,    // (32,256,2048)
    const unsigned short* __restrict__ rprojT,  // (256,256)
    float* __restrict__ S)                      // (32,2048)
{
    const int b  = blockIdx.z;
    const int n0 = blockIdx.x * 128;
    const int d0 = blockIdx.y * 128;

    __shared__ unsigned short Al[128 * 32];
    __shared__ unsigned short Bl[128 * 32];
    __shared__ float ssq[128];

    const int tid  = threadIdx.x;
    const int w    = tid >> 6;
    const int lane = tid & 63;
    const int l16  = lane & 15;
    const int quad = lane >> 4;
    const int wm   = w >> 1, wn = w & 1;

    if (tid < 128) ssq[tid] = 0.f;

    f32x4 acc[4][4] = {};

    const unsigned short* curB = curb + (size_t)b * 2048 * 256;
    const unsigned short* preB = preT + (size_t)b * 256 * 2048;

    const int srow  = lane >> 2;        // 0..15
    const int sbyte = (lane & 3) * 16;  // bytes within 64B row-chunk

    for (int kt = 0; kt < 72; ++kt) {
        const unsigned short *ab, *bb;
        size_t as, bs;
        if (kt < 64) {
            const int k0 = kt * 32;
            ab = Wneg + (size_t)n0 * 2048 + k0; as = 2048;
            bb = preB + (size_t)d0 * 2048 + k0; bs = 2048;
        } else {
            const int kk = kt * 32 - 2048;
            ab = curB + (size_t)n0 * 256 + kk;   as = 256;
            bb = rprojT + (size_t)d0 * 256 + kk; bs = 256;
        }
        __syncthreads();  // previous tile fully consumed
#pragma unroll
        for (int j = 0; j < 2; ++j) {
            const int row = w * 32 + j * 16 + srow;
            GLL16((const char*)(ab + row * as) + sbyte, (char*)Al + w * 2048 + j * 1024);
            GLL16((const char*)(bb + row * bs) + sbyte, (char*)Bl + w * 2048 + j * 1024);
        }
        __syncthreads();  // staging visible

        bf16x8 af[4], bfr[4];
#pragma unroll
        for (int mi = 0; mi < 4; ++mi)
            af[mi] = *(const bf16x8*)(Al + (wm * 64 + mi * 16 + l16) * 32 + quad * 8);
#pragma unroll
        for (int ni = 0; ni < 4; ++ni)
            bfr[ni] = *(const bf16x8*)(Bl + (wn * 64 + ni * 16 + l16) * 32 + quad * 8);
#pragma unroll
        for (int mi = 0; mi < 4; ++mi)
#pragma unroll
            for (int ni = 0; ni < 4; ++ni)
                acc[mi][ni] = __builtin_amdgcn_mfma_f32_16x16x32_bf16(
                    af[mi], bfr[ni], acc[mi][ni], 0, 0, 0);
    }
    __syncthreads();

    // C/D layout: col = lane&15 (d), row = quad*4 + reg (n) [verified m89/m91]
#pragma unroll
    for (int mi = 0; mi < 4; ++mi)
#pragma unroll
        for (int r = 0; r < 4; ++r) {
            float s = 0.f;
#pragma unroll
            for (int ni = 0; ni < 4; ++ni) {
                float v = acc[mi][ni][r];
                s += v * v;
            }
            s += __shfl_xor(s, 1);
            s += __shfl_xor(s, 2);
            s += __shfl_xor(s, 4);
            s += __shfl_xor(s, 8);
            if (l16 == 0)
                atomicAdd(&ssq[wm * 64 + mi * 16 + quad * 4 + r], s);
        }
    __syncthreads();
    if (tid < 128)
        atomicAdd(&S[(size_t)b * 2048 + n0 + tid], ssq[tid]);
}

// --------------------------------------------------------------------------
// finalize: loss[b] = 0.2 * sum_n sqrt(S[b,n]) + Csum
// --------------------------------------------------------------------------
__global__ void finalize(const float* __restrict__ S, const float* __restrict__ csum,
                         float* __restrict__ out) {
    const int b = blockIdx.x;
    float s = 0.f;
    for (int i = threadIdx.x; i < 2048; i += 256)
        s += sqrtf(S[(size_t)b * 2048 + i]);
#pragma unroll
    for (int off = 32; off; off >>= 1) s += __shfl_down(s, off);
    __shared__ float sm[4];
    int wv = threadIdx.x >> 6, ln = threadIdx.x & 63;
    if (ln == 0) sm[wv] = s;
    __syncthreads();
    if (threadIdx.x == 0)
        out[b] = 0.2f * (sm[0] + sm[1] + sm[2] + sm[3]) + csum[0];
}

// --------------------------------------------------------------------------
extern "C" void kernel_launch(void* const* d_in, const int* in_sizes, int n_in,
                              void* d_out, int out_size, void* d_ws, size_t ws_size,
                              hipStream_t stream) {
    const float* cur    = (const float*)d_in[0];  // (32,2048,256)
    const float* pre    = (const float*)d_in[1];  // (32,2048,256)
    const float* r_proj = (const float*)d_in[2];  // (256,256)
    const float* inc    = (const float*)d_in[3];  // (2048,2048)
    float* out = (float*)d_out;                   // [0..31]=loss, [32..]=incidence

    char* ws = (char*)d_ws;
    unsigned short* Wneg   = (unsigned short*)(ws + 0);          //  8 MB
    unsigned short* curb   = (unsigned short*)(ws + 8388608);    // 32 MB
    unsigned short* preT   = (unsigned short*)(ws + 41943040);   // 32 MB
    unsigned short* rprojT = (unsigned short*)(ws + 75497472);   // 128 KB
    float*          Sbuf   = (float*)(ws + 75628544);            // 256 KB
    float*          csum   = (float*)(ws + 75890688);            // 4 B

    hipMemsetAsync(ws + 75628544, 0, 262148, stream);  // S + csum

    prep_all<<<8208, 256, 0, stream>>>(inc, out + 32, Wneg, csum,
                                       cur, curb, pre, preT, r_proj, rprojT);
    gemm_diff<<<dim3(16, 2, 32), 256, 0, stream>>>(Wneg, curb, preT, rprojT, Sbuf);
    finalize<<<32, 256, 0, stream>>>(Sbuf, csum, out);
}

// Round 3
// 255.362 us; speedup vs baseline: 1.2344x; 1.1957x over previous
//
#include <hip/hip_runtime.h>

// ---------------------------------------------------------------------------
// TemporalHyperedge: loss[b] = 0.2 * sum_n ||cur[b]@r_proj - W@pre[b]||_2
//                              + sum_n (max_m W[n,m] + 0.001*||W[n,:]||_2)
// W = incidence_m masked to > 0.01. Output = [loss(32) , incidence_m(2048^2)].
//
// R2 changes:
//  - gemm: block = 128n x 256d (full D). 2x reuse of A per staged byte,
//    32 MFMA/wave per barrier, 512 blocks = exactly 2/CU, S written without
//    atomics (sqrt fused), no workspace memset needed.
//  - prep: csum single-address atomic (2048-way serialized) -> per-row array.
// ---------------------------------------------------------------------------

typedef __attribute__((ext_vector_type(8))) short bf16x8;
typedef __attribute__((ext_vector_type(8))) unsigned short ushort8;
typedef __attribute__((ext_vector_type(4))) float f32x4;

__device__ __forceinline__ unsigned short f2bf(float f) {
    union { float f; unsigned u; } x; x.f = f;
    unsigned r = x.u + 0x7fffu + ((x.u >> 16) & 1u);   // RNE
    return (unsigned short)(r >> 16);
}

#define GLL16(g, l)                                                         \
    __builtin_amdgcn_global_load_lds(                                       \
        (const __attribute__((address_space(1))) void*)(g),                 \
        (__attribute__((address_space(3))) void*)(l), 16, 0, 0)

// --------------------------------------------------------------------------
// 64x64 f32->bf16 transpose tile helper (LDS pitch 66 shorts).
// --------------------------------------------------------------------------
__device__ __forceinline__ void transpose_64x64(
    const float* __restrict__ src, unsigned short* __restrict__ dst,
    int R, int C, int r0, int c0, unsigned short* __restrict__ tile) {
    const int t = threadIdx.x;
    const int fr = t >> 4, fc = (t & 15) * 4;
#pragma unroll
    for (int it = 0; it < 4; ++it) {
        int m = fr + it * 16;
        float4 v = *(const float4*)(src + (size_t)(r0 + m) * C + c0 + fc);
        unsigned short* p = tile + m * 66 + fc;
        ushort2 a, b;
        a.x = f2bf(v.x); a.y = f2bf(v.y);
        b.x = f2bf(v.z); b.y = f2bf(v.w);
        *(ushort2*)(p) = a;
        *(ushort2*)(p + 2) = b;
    }
    __syncthreads();
#pragma unroll
    for (int pss = 0; pss < 2; ++pss) {
        int d = (t >> 3) + pss * 32;
        int m8 = (t & 7) * 8;
        unsigned short r[8];
#pragma unroll
        for (int j = 0; j < 8; ++j) r[j] = tile[(m8 + j) * 66 + d];
        ushort8 pk;
        pk[0] = r[0]; pk[1] = r[1]; pk[2] = r[2]; pk[3] = r[3];
        pk[4] = r[4]; pk[5] = r[5]; pk[6] = r[6]; pk[7] = r[7];
        *(ushort8*)(dst + (size_t)(c0 + d) * R + r0 + m8) = pk;
    }
}

// --------------------------------------------------------------------------
// prep_all — block sections:
//   [0,2048)    : incidence row: copy-out, -masked bf16 W, crow[row]=l1+1e-3*l2
//   [2048,4096) : cur f32 -> bf16 flat convert
//   [4096,8192) : pre (32,2048,256) -> preT (32,256,2048) bf16 transpose
//   [8192,8208) : r_proj (256,256) -> rprojT bf16 transpose
// --------------------------------------------------------------------------
__global__ __launch_bounds__(256) void prep_all(
    const float* __restrict__ inc, float* __restrict__ out_inc,
    unsigned short* __restrict__ Wneg, float* __restrict__ crow,
    const float* __restrict__ cur, unsigned short* __restrict__ curb,
    const float* __restrict__ pre, unsigned short* __restrict__ preT,
    const float* __restrict__ r_proj, unsigned short* __restrict__ rprojT) {
    __shared__ unsigned short tile[64 * 66];
    __shared__ float smax[4], ssum[4];
    const int bid = blockIdx.x;
    const int t = threadIdx.x;

    if (bid < 2048) {
        const int row = bid;
        const float4* src = (const float4*)(inc + (size_t)row * 2048);
        float4* dst = (float4*)(out_inc + (size_t)row * 2048);
        ushort4* wp = (ushort4*)(Wneg + (size_t)row * 2048);
        float lmax = 0.f, ss = 0.f;
#pragma unroll
        for (int it = 0; it < 2; ++it) {
            int i = it * 256 + t;
            float4 v = src[i];
            dst[i] = v;
            float w0 = v.x > 0.01f ? v.x : 0.f;
            float w1 = v.y > 0.01f ? v.y : 0.f;
            float w2 = v.z > 0.01f ? v.z : 0.f;
            float w3 = v.w > 0.01f ? v.w : 0.f;
            ushort4 p;
            p.x = f2bf(-w0); p.y = f2bf(-w1); p.z = f2bf(-w2); p.w = f2bf(-w3);
            wp[i] = p;
            lmax = fmaxf(lmax, fmaxf(fmaxf(w0, w1), fmaxf(w2, w3)));
            ss += w0 * w0 + w1 * w1 + w2 * w2 + w3 * w3;
        }
#pragma unroll
        for (int off = 32; off; off >>= 1) {
            lmax = fmaxf(lmax, __shfl_down(lmax, off));
            ss += __shfl_down(ss, off);
        }
        int wv = t >> 6, ln = t & 63;
        if (ln == 0) { smax[wv] = lmax; ssum[wv] = ss; }
        __syncthreads();
        if (t == 0) {
            float m = fmaxf(fmaxf(smax[0], smax[1]), fmaxf(smax[2], smax[3]));
            float s = ssum[0] + ssum[1] + ssum[2] + ssum[3];
            crow[row] = m + 0.001f * sqrtf(s);   // no atomic
        }
    } else if (bid < 4096) {
        const size_t base = (size_t)(bid - 2048) * 2048;
#pragma unroll
        for (int it = 0; it < 8; ++it) {
            size_t i = base + it * 256 + t;
            float4 v = ((const float4*)cur)[i];
            ushort4 p;
            p.x = f2bf(v.x); p.y = f2bf(v.y); p.z = f2bf(v.z); p.w = f2bf(v.w);
            ((ushort4*)curb)[i] = p;
        }
    } else if (bid < 8192) {
        const int tt = bid - 4096;
        const int b = tt >> 7;
        const int mt = (tt & 127) >> 2;
        const int dt = tt & 3;
        transpose_64x64(pre + (size_t)b * 524288, preT + (size_t)b * 524288,
                        2048, 256, mt * 64, dt * 64, tile);
    } else {
        const int tt = bid - 8192;
        transpose_64x64(r_proj, rprojT, 256, 256, (tt >> 2) * 64, (tt & 3) * 64,
                        tile);
    }
}

// --------------------------------------------------------------------------
// gemm_diff: block = 128n x 256d (full D), BK=32, K=2304.
// 256 threads = 4 waves in 2x2 (wm: 64n halves, wn: 128d halves);
// each wave: 4x8 grid of 16x16x32 MFMAs = 32 MFMA per k-tile.
// Epilogue: sum_d diff^2 -> Ssq[b,n] = sqrt(...), plain store (one block owns
// each (b,n) row — no atomics).
// --------------------------------------------------------------------------
__global__ __launch_bounds__(256, 2) void gemm_diff(
    const unsigned short* __restrict__ Wneg,    // (2048,2048)
    const unsigned short* __restrict__ curb,    // (32,2048,256)
    const unsigned short* __restrict__ preT,    // (32,256,2048)
    const unsigned short* __restrict__ rprojT,  // (256,256)
    float* __restrict__ Ssq)                    // (32,2048) sqrt of sums
{
    const int n0 = blockIdx.x * 128;
    const int b  = blockIdx.y;

    __shared__ unsigned short Al[128 * 32];   //  8 KB
    __shared__ unsigned short Bl[256 * 32];   // 16 KB
    __shared__ float ssq[128];

    const int tid  = threadIdx.x;
    const int w    = tid >> 6;
    const int lane = tid & 63;
    const int l16  = lane & 15;
    const int quad = lane >> 4;
    const int wm   = w >> 1, wn = w & 1;

    if (tid < 128) ssq[tid] = 0.f;

    f32x4 acc[4][8] = {};

    const unsigned short* curB = curb + (size_t)b * 2048 * 256;
    const unsigned short* preB = preT + (size_t)b * 256 * 2048;

    const int srow  = lane >> 2;        // 0..15
    const int sbyte = (lane & 3) * 16;  // byte offset within 64B row-chunk

    for (int kt = 0; kt < 72; ++kt) {
        const unsigned short *ab, *bb;
        size_t as, bs;
        if (kt < 64) {
            const int k0 = kt * 32;
            ab = Wneg + (size_t)n0 * 2048 + k0; as = 2048;
            bb = preB + k0;                     bs = 2048;
        } else {
            const int kk = kt * 32 - 2048;
            ab = curB + (size_t)n0 * 256 + kk;  as = 256;
            bb = rprojT + kk;                   bs = 256;
        }
        __syncthreads();  // previous tile fully consumed
        // A: wave w stages rows [w*32, w*32+32)
#pragma unroll
        for (int j = 0; j < 2; ++j) {
            const int row = w * 32 + j * 16 + srow;
            GLL16((const char*)(ab + row * as) + sbyte,
                  (char*)Al + w * 2048 + j * 1024);
        }
        // B: wave w stages rows (d) [w*64, w*64+64)
#pragma unroll
        for (int j = 0; j < 4; ++j) {
            const int row = w * 64 + j * 16 + srow;
            GLL16((const char*)(bb + row * bs) + sbyte,
                  (char*)Bl + w * 4096 + j * 1024);
        }
        __syncthreads();  // staging visible

        bf16x8 af[4], bfr[8];
#pragma unroll
        for (int mi = 0; mi < 4; ++mi)
            af[mi] = *(const bf16x8*)(Al + (wm * 64 + mi * 16 + l16) * 32 + quad * 8);
#pragma unroll
        for (int ni = 0; ni < 8; ++ni)
            bfr[ni] = *(const bf16x8*)(Bl + (wn * 128 + ni * 16 + l16) * 32 + quad * 8);
#pragma unroll
        for (int mi = 0; mi < 4; ++mi)
#pragma unroll
            for (int ni = 0; ni < 8; ++ni)
                acc[mi][ni] = __builtin_amdgcn_mfma_f32_16x16x32_bf16(
                    af[mi], bfr[ni], acc[mi][ni], 0, 0, 0);
    }
    __syncthreads();

    // C/D layout: col = lane&15 (d), row = quad*4 + reg (n) [verified m89/m91]
#pragma unroll
    for (int mi = 0; mi < 4; ++mi)
#pragma unroll
        for (int r = 0; r < 4; ++r) {
            float s = 0.f;
#pragma unroll
            for (int ni = 0; ni < 8; ++ni) {
                float v = acc[mi][ni][r];
                s += v * v;
            }
            s += __shfl_xor(s, 1);
            s += __shfl_xor(s, 2);
            s += __shfl_xor(s, 4);
            s += __shfl_xor(s, 8);
            if (l16 == 0)   // 2-way (wn=0,1) accumulate in LDS
                atomicAdd(&ssq[wm * 64 + mi * 16 + quad * 4 + r], s);
        }
    __syncthreads();
    if (tid < 128)
        Ssq[(size_t)b * 2048 + n0 + tid] = sqrtf(ssq[tid]);
}

// --------------------------------------------------------------------------
// finalize: loss[b] = 0.2 * sum_n Ssq[b,n] + sum_n crow[n]
// --------------------------------------------------------------------------
__global__ void finalize(const float* __restrict__ Ssq,
                         const float* __restrict__ crow,
                         float* __restrict__ out) {
    const int b = blockIdx.x;
    float s1 = 0.f, s2 = 0.f;
    for (int i = threadIdx.x; i < 2048; i += 256) {
        s1 += Ssq[(size_t)b * 2048 + i];
        s2 += crow[i];
    }
#pragma unroll
    for (int off = 32; off; off >>= 1) {
        s1 += __shfl_down(s1, off);
        s2 += __shfl_down(s2, off);
    }
    __shared__ float sm1[4], sm2[4];
    int wv = threadIdx.x >> 6, ln = threadIdx.x & 63;
    if (ln == 0) { sm1[wv] = s1; sm2[wv] = s2; }
    __syncthreads();
    if (threadIdx.x == 0)
        out[b] = 0.2f * (sm1[0] + sm1[1] + sm1[2] + sm1[3])
               + (sm2[0] + sm2[1] + sm2[2] + sm2[3]);
}

// --------------------------------------------------------------------------
extern "C" void kernel_launch(void* const* d_in, const int* in_sizes, int n_in,
                              void* d_out, int out_size, void* d_ws, size_t ws_size,
                              hipStream_t stream) {
    const float* cur    = (const float*)d_in[0];  // (32,2048,256)
    const float* pre    = (const float*)d_in[1];  // (32,2048,256)
    const float* r_proj = (const float*)d_in[2];  // (256,256)
    const float* inc    = (const float*)d_in[3];  // (2048,2048)
    float* out = (float*)d_out;                   // [0..31]=loss, [32..]=incidence

    char* ws = (char*)d_ws;
    unsigned short* Wneg   = (unsigned short*)(ws + 0);          //  8 MB
    unsigned short* curb   = (unsigned short*)(ws + 8388608);    // 32 MB
    unsigned short* preT   = (unsigned short*)(ws + 41943040);   // 32 MB
    unsigned short* rprojT = (unsigned short*)(ws + 75497472);   // 128 KB
    float*          Sbuf   = (float*)(ws + 75628544);            // 256 KB
    float*          crow   = (float*)(ws + 75890688);            // 8 KB

    prep_all<<<8208, 256, 0, stream>>>(inc, out + 32, Wneg, crow,
                                       cur, curb, pre, preT, r_proj, rprojT);
    gemm_diff<<<dim3(16, 32), 256, 0, stream>>>(Wneg, curb, preT, rprojT, Sbuf);
    finalize<<<32, 256, 0, stream>>>(Sbuf, crow, out);
}